// Round 1
// baseline (1082.964 us; speedup 1.0000x reference)
//
#include <hip/hip_runtime.h>
#include <math.h>

typedef unsigned short u16;
typedef __attribute__((ext_vector_type(4))) float f32x4;
typedef __attribute__((ext_vector_type(8))) __bf16 bf16x8;
typedef __attribute__((ext_vector_type(4))) unsigned short u16x4;
typedef __attribute__((ext_vector_type(8))) unsigned short u16x8;

// async global->LDS, 16B per lane; LDS dest must be wave-uniform base + lane*16
#define GLL16(gp, lp) __builtin_amdgcn_global_load_lds( \
    (__attribute__((address_space(1))) void*)(void*)(gp), \
    (__attribute__((address_space(3))) void*)(void*)(lp), 16, 0, 0)

__device__ __forceinline__ u16 f2bf(float x) {            // RNE
    unsigned u = __float_as_uint(x);
    return (u16)((u + 0x7FFFu + ((u >> 16) & 1u)) >> 16);
}
__device__ __forceinline__ float bf2f(u16 h) { return __uint_as_float(((unsigned)h) << 16); }

__device__ __forceinline__ f32x4 mfma16(bf16x8 a, bf16x8 b, f32x4 c) {
    return __builtin_amdgcn_mfma_f32_16x16x32_bf16(a, b, c, 0, 0, 0);
}

// ---------------- fp32 -> bf16 conversion ----------------
__global__ void cvt_f32_bf16(const float* __restrict__ s, u16* __restrict__ d, int n4) {
    int i = blockIdx.x * 256 + threadIdx.x;
    if (i < n4) {
        float4 v = ((const float4*)s)[i];
        u16x4 o = { f2bf(v.x), f2bf(v.y), f2bf(v.z), f2bf(v.w) };
        ((u16x4*)d)[i] = o;
    }
}

// ---------------- rope table: cos/sin of 2*theta (double rotary = rotate by 2theta) ----
__global__ void rope_table_k(float2* __restrict__ tab) {
    int id = blockIdx.x * 256 + threadIdx.x;   // 2048*64
    int t = id >> 6, j = id & 63;
    // inv_freq = 10000^(-2j/128); angle = 2 * t * inv_freq
    float freq = exp2f(-((float)(2 * j) / 128.f) * 13.287712379549449f);
    float ang = 2.f * (float)t * freq;
    float sv, cv;
    sincosf(ang, &sv, &cv);
    float2 r; r.x = cv; r.y = sv;
    tab[id] = r;
}

// ---------------- apply rotary in place on (B,T,H,128) bf16 tensor ----------------
__global__ void rope_apply_k(u16* __restrict__ X, const float2* __restrict__ tab) {
    const int id = blockIdx.x * 256 + threadIdx.x;   // 2^20 threads
    const int j8 = id & 7, h = (id >> 3) & 15, t = (id >> 7) & 2047, b = id >> 18;
    u16* p1 = X + (((size_t)(b * 2048 + t) * 16 + h) * 128) + j8 * 8;
    u16* p2 = p1 + 64;
    u16x8 a = *(const u16x8*)p1;
    u16x8 c2 = *(const u16x8*)p2;
    const float2* tb = tab + t * 64 + j8 * 8;
#pragma unroll
    for (int i = 0; i < 8; ++i) {
        float x1 = bf2f(a[i]), x2 = bf2f(c2[i]);
        float2 cs = tb[i];
        a[i]  = f2bf(x1 * cs.x + x2 * cs.y);
        c2[i] = f2bf(x2 * cs.x - x1 * cs.y);
    }
    *(u16x8*)p1 = a;
    *(u16x8*)p2 = c2;
}

// ---------------- NT GEMM: C[m][n] = sum_k A[m][k] * B[n][k], 128x128 tile, BK=32 ----
// MODE 0: fused QKV -> writes Q,K (B,T,H,D layout == row-major M x 2048) and V transposed (B,H,D,T)
// MODE 1: writes fp32 Out (M x 2048)
template <int MODE>
__global__ __launch_bounds__(256) void gemm_nt(const u16* __restrict__ A, const u16* __restrict__ Bw,
                                               u16* __restrict__ Qo, u16* __restrict__ Ko,
                                               u16* __restrict__ Vt, float* __restrict__ Out, int K) {
    __shared__ u16 As[128 * 32];
    __shared__ u16 Bs[128 * 32];
    const int tid = threadIdx.x;
    const int lane = tid & 63;
    const int qd = lane >> 4, ln = lane & 15;
    const int wid = tid >> 6;
    const int wx = wid & 1, wy = wid >> 1;
    const int m0 = blockIdx.x * 128, n0 = blockIdx.y * 128;
    const int c0 = tid, c1 = tid + 256;     // 512 chunks of 16B per 8KB tile

    const u16* ga0 = A + (size_t)(m0 + (c0 >> 2)) * K + (c0 & 3) * 8;
    const u16* ga1 = A + (size_t)(m0 + (c1 >> 2)) * K + (c1 & 3) * 8;
    const u16* gb0 = Bw + (size_t)(n0 + (c0 >> 2)) * K + (c0 & 3) * 8;
    const u16* gb1 = Bw + (size_t)(n0 + (c1 >> 2)) * K + (c1 & 3) * 8;
    u16* la0 = &As[c0 * 8]; u16* la1 = &As[c1 * 8];
    u16* lb0 = &Bs[c0 * 8]; u16* lb1 = &Bs[c1 * 8];

    f32x4 acc[4][4];
#pragma unroll
    for (int mi = 0; mi < 4; ++mi)
#pragma unroll
        for (int ni = 0; ni < 4; ++ni) acc[mi][ni] = f32x4{0.f, 0.f, 0.f, 0.f};

    const int aoffb = (wy * 64 + ln) * 32 + qd * 8;
    const int boffb = (wx * 64 + ln) * 32 + qd * 8;

    const int niter = K >> 5;
    for (int kt = 0; kt < niter; ++kt) {
        __syncthreads();
        GLL16(ga0, la0); GLL16(ga1, la1);
        GLL16(gb0, lb0); GLL16(gb1, lb1);
        ga0 += 32; ga1 += 32; gb0 += 32; gb1 += 32;
        __syncthreads();
        bf16x8 af[4], bfr[4];
#pragma unroll
        for (int i = 0; i < 4; ++i) af[i] = *(const bf16x8*)&As[aoffb + i * 512];
#pragma unroll
        for (int i = 0; i < 4; ++i) bfr[i] = *(const bf16x8*)&Bs[boffb + i * 512];
#pragma unroll
        for (int mi = 0; mi < 4; ++mi)
#pragma unroll
            for (int ni = 0; ni < 4; ++ni)
                acc[mi][ni] = mfma16(af[mi], bfr[ni], acc[mi][ni]);
    }

    const int mg0 = m0 + wy * 64 + qd * 4;
    const int ng0 = n0 + wx * 64 + ln;
    if constexpr (MODE == 0) {
        const int sec = n0 >> 11;   // 0=Q 1=K 2=V, uniform per block
#pragma unroll
        for (int mi = 0; mi < 4; ++mi)
#pragma unroll
            for (int ni = 0; ni < 4; ++ni) {
                const int ng = ng0 + ni * 16;
#pragma unroll
                for (int r = 0; r < 4; ++r) {
                    const int m = mg0 + mi * 16 + r;
                    const u16 v = f2bf(acc[mi][ni][r]);
                    if (sec == 0) {
                        Qo[(size_t)m * 2048 + ng] = v;
                    } else if (sec == 1) {
                        Ko[(size_t)m * 2048 + (ng - 2048)] = v;
                    } else {
                        const int bb = m >> 11, t = m & 2047, hd = ng - 4096;
                        Vt[((size_t)bb * 2048 + hd) * 2048 + t] = v;   // (B,H,D,T)
                    }
                }
            }
    } else {
#pragma unroll
        for (int mi = 0; mi < 4; ++mi)
#pragma unroll
            for (int ni = 0; ni < 4; ++ni) {
                const int ng = ng0 + ni * 16;
#pragma unroll
                for (int r = 0; r < 4; ++r)
                    Out[(size_t)(mg0 + mi * 16 + r) * 2048 + ng] = acc[mi][ni][r];
            }
    }
}

// ---------------- causal flash attention ----------------
// grid (T/128, B*H). block 256 = 4 waves; wave w owns Q rows [w*32, w*32+32).
// K/V tiles 64 wide. Q LDS buffer reused as P (128x64 bf16). LDS total = 64KB.
__global__ __launch_bounds__(256) void attn_kernel(const u16* __restrict__ Qb, const u16* __restrict__ Kb,
                                                   const u16* __restrict__ Vt, u16* __restrict__ Yb) {
    __shared__ u16 Qs[128 * 128];   // 32KB; reused as P[128][64] after Q frags cached
    __shared__ u16 Ks[64 * 128];    // 16KB  [s][d]
    __shared__ u16 Vs[128 * 64];    // 16KB  [d][s]
    const int tid = threadIdx.x;
    const int lane = tid & 63;
    const int qd = lane >> 4, ln = lane & 15;
    const int wid = tid >> 6;
    const int wr = wid * 32;
    const int qt = blockIdx.x, bh = blockIdx.y;
    const int b = bh >> 4, h = bh & 15;
    const int q0 = qt * 128;
    const float scl = 0.088388347762f * 1.44269504089f;  // (1/sqrt(128)) * log2(e)

    // stage Q tile (128 x 128 bf16)
#pragma unroll
    for (int p = 0; p < 8; ++p) {
        int c = p * 256 + tid;
        GLL16(Qb + ((size_t)((b * 2048 + q0 + (c >> 4)) * 16 + h)) * 128 + (c & 15) * 8, &Qs[c * 8]);
    }
    __syncthreads();
    bf16x8 qf[2][4];   // A-frags for this wave's 32 rows, all 4 k-steps
#pragma unroll
    for (int mi = 0; mi < 2; ++mi)
#pragma unroll
        for (int ks = 0; ks < 4; ++ks)
            qf[mi][ks] = *(const bf16x8*)&Qs[(wr + mi * 16 + ln) * 128 + ks * 32 + qd * 8];

    f32x4 o[2][8];
#pragma unroll
    for (int mi = 0; mi < 2; ++mi)
#pragma unroll
        for (int di = 0; di < 8; ++di) o[mi][di] = f32x4{0.f, 0.f, 0.f, 0.f};
    float Mr[2][4], Lr[2][4];
#pragma unroll
    for (int mi = 0; mi < 2; ++mi)
#pragma unroll
        for (int r = 0; r < 4; ++r) { Mr[mi][r] = -1e30f; Lr[mi][r] = 0.f; }

    const int nkt = 2 * qt + 2;    // causal: k tiles cover keys [0, q0+128)
    for (int kt = 0; kt < nkt; ++kt) {
        const int k0 = kt * 64;
        __syncthreads();   // previous iteration's LDS reads complete
#pragma unroll
        for (int p = 0; p < 4; ++p) {  // K tile: 64 rows x 128 d
            int c = p * 256 + tid;
            GLL16(Kb + ((size_t)((b * 2048 + k0 + (c >> 4)) * 16 + h)) * 128 + (c & 15) * 8, &Ks[c * 8]);
        }
#pragma unroll
        for (int p = 0; p < 4; ++p) {  // V tile (transposed): 128 d x 64 s
            int c = p * 256 + tid;
            GLL16(Vt + ((size_t)((b * 16 + h) * 128 + (c >> 3))) * 2048 + k0 + (c & 7) * 8, &Vs[c * 8]);
        }
        __syncthreads();

        // S = Q K^T  (wave rows 32 x tile cols 64)
        f32x4 s[2][4];
#pragma unroll
        for (int mi = 0; mi < 2; ++mi)
#pragma unroll
            for (int ni = 0; ni < 4; ++ni) s[mi][ni] = f32x4{0.f, 0.f, 0.f, 0.f};
#pragma unroll
        for (int ks = 0; ks < 4; ++ks) {
            bf16x8 kf[4];
#pragma unroll
            for (int ni = 0; ni < 4; ++ni)
                kf[ni] = *(const bf16x8*)&Ks[(ni * 16 + ln) * 128 + ks * 32 + qd * 8];
#pragma unroll
            for (int mi = 0; mi < 2; ++mi)
#pragma unroll
                for (int ni = 0; ni < 4; ++ni)
                    s[mi][ni] = mfma16(qf[mi][ks], kf[ni], s[mi][ni]);
        }
        // scale (log2 domain) + causal mask
#pragma unroll
        for (int mi = 0; mi < 2; ++mi)
#pragma unroll
            for (int ni = 0; ni < 4; ++ni)
#pragma unroll
                for (int r = 0; r < 4; ++r) {
                    int qi = q0 + wr + mi * 16 + qd * 4 + r;
                    int ki = k0 + ni * 16 + ln;
                    float v = (float)s[mi][ni][r] * scl;
                    s[mi][ni][r] = (ki > qi) ? -1e30f : v;
                }
        // row max across 4 ni + 16 lanes of the quad
        float rx[2][4];
#pragma unroll
        for (int mi = 0; mi < 2; ++mi)
#pragma unroll
            for (int r = 0; r < 4; ++r) {
                float m = -1e30f;
#pragma unroll
                for (int ni = 0; ni < 4; ++ni) m = fmaxf(m, s[mi][ni][r]);
                rx[mi][r] = m;
            }
#pragma unroll
        for (int st = 1; st < 16; st <<= 1)
#pragma unroll
            for (int mi = 0; mi < 2; ++mi)
#pragma unroll
                for (int r = 0; r < 4; ++r)
                    rx[mi][r] = fmaxf(rx[mi][r], __shfl_xor(rx[mi][r], st));
        // online update
        float al[2][4];
#pragma unroll
        for (int mi = 0; mi < 2; ++mi)
#pragma unroll
            for (int r = 0; r < 4; ++r) {
                float nm = fmaxf(Mr[mi][r], rx[mi][r]);
                al[mi][r] = exp2f(Mr[mi][r] - nm);
                Mr[mi][r] = nm;
            }
        float rs[2][4];
#pragma unroll
        for (int mi = 0; mi < 2; ++mi)
#pragma unroll
            for (int r = 0; r < 4; ++r) rs[mi][r] = 0.f;
#pragma unroll
        for (int mi = 0; mi < 2; ++mi)
#pragma unroll
            for (int ni = 0; ni < 4; ++ni)
#pragma unroll
                for (int r = 0; r < 4; ++r) {
                    float p = exp2f(s[mi][ni][r] - Mr[mi][r]);
                    s[mi][ni][r] = p;
                    rs[mi][r] += p;
                }
#pragma unroll
        for (int st = 1; st < 16; st <<= 1)
#pragma unroll
            for (int mi = 0; mi < 2; ++mi)
#pragma unroll
                for (int r = 0; r < 4; ++r)
                    rs[mi][r] += __shfl_xor(rs[mi][r], st);
#pragma unroll
        for (int mi = 0; mi < 2; ++mi)
#pragma unroll
            for (int r = 0; r < 4; ++r) Lr[mi][r] = Lr[mi][r] * al[mi][r] + rs[mi][r];
#pragma unroll
        for (int mi = 0; mi < 2; ++mi)
#pragma unroll
            for (int di = 0; di < 8; ++di)
#pragma unroll
                for (int r = 0; r < 4; ++r) o[mi][di][r] *= al[mi][r];
        // P (C-layout regs) -> LDS row-major [m][s] bf16
#pragma unroll
        for (int mi = 0; mi < 2; ++mi)
#pragma unroll
            for (int ni = 0; ni < 4; ++ni)
#pragma unroll
                for (int r = 0; r < 4; ++r)
                    Qs[(wr + mi * 16 + qd * 4 + r) * 64 + ni * 16 + ln] = f2bf(s[mi][ni][r]);
        __syncthreads();
        // O += P * V   (A = P rows, B = Vt rows d)
#pragma unroll
        for (int ks2 = 0; ks2 < 2; ++ks2) {
            bf16x8 pf[2];
#pragma unroll
            for (int mi = 0; mi < 2; ++mi)
                pf[mi] = *(const bf16x8*)&Qs[(wr + mi * 16 + ln) * 64 + ks2 * 32 + qd * 8];
#pragma unroll
            for (int di = 0; di < 8; ++di) {
                bf16x8 vf = *(const bf16x8*)&Vs[(di * 16 + ln) * 64 + ks2 * 32 + qd * 8];
#pragma unroll
                for (int mi = 0; mi < 2; ++mi)
                    o[mi][di] = mfma16(pf[mi], vf, o[mi][di]);
            }
        }
    }
    // finalize: O / L, write Y (B,T,H,D) bf16
    float inv[2][4];
#pragma unroll
    for (int mi = 0; mi < 2; ++mi)
#pragma unroll
        for (int r = 0; r < 4; ++r) inv[mi][r] = 1.f / Lr[mi][r];
#pragma unroll
    for (int mi = 0; mi < 2; ++mi)
#pragma unroll
        for (int di = 0; di < 8; ++di)
#pragma unroll
            for (int r = 0; r < 4; ++r) {
                int t = q0 + wr + mi * 16 + qd * 4 + r;
                int d = di * 16 + ln;
                Yb[((size_t)((b * 2048 + t) * 16 + h)) * 128 + d] = f2bf(o[mi][di][r] * inv[mi][r]);
            }
}

// ---------------- launch ----------------
extern "C" void kernel_launch(void* const* d_in, const int* in_sizes, int n_in,
                              void* d_out, int out_size, void* d_ws, size_t ws_size,
                              hipStream_t stream) {
    const float* x  = (const float*)d_in[0];
    const float* wq = (const float*)d_in[1];
    const float* wk = (const float*)d_in[2];
    const float* wv = (const float*)d_in[3];
    const float* wo = (const float*)d_in[4];
    float* out = (float*)d_out;
    char* ws = (char*)d_ws;

    u16* xb     = (u16*)(ws);                          // 8192x2048 bf16 (33.5MB); reused as Y after attn
    u16* wqkv   = (u16*)(ws + (size_t)33554432);       // 6144x2048 bf16
    u16* wob    = (u16*)(ws + (size_t)58720256);       // 2048x2048 bf16
    u16* Qb     = (u16*)(ws + (size_t)67108864);       // (B,T,H,D) bf16
    u16* Kb     = (u16*)(ws + (size_t)100663296);      // (B,T,H,D) bf16
    u16* Vt     = (u16*)(ws + (size_t)134217728);      // (B,H,D,T) bf16
    float2* tab = (float2*)(ws + (size_t)167772160);   // 2048x64 cos/sin(2theta)
    u16* Yb = xb;

    cvt_f32_bf16<<<16384, 256, 0, stream>>>(x, xb, 4194304);
    cvt_f32_bf16<<<4096, 256, 0, stream>>>(wq, wqkv, 1048576);
    cvt_f32_bf16<<<4096, 256, 0, stream>>>(wk, wqkv + 4194304, 1048576);
    cvt_f32_bf16<<<4096, 256, 0, stream>>>(wv, wqkv + 8388608, 1048576);
    cvt_f32_bf16<<<4096, 256, 0, stream>>>(wo, wob, 1048576);
    rope_table_k<<<512, 256, 0, stream>>>(tab);

    gemm_nt<0><<<dim3(64, 48), 256, 0, stream>>>(xb, wqkv, Qb, Kb, Vt, nullptr, 2048);
    rope_apply_k<<<4096, 256, 0, stream>>>(Qb, tab);
    rope_apply_k<<<4096, 256, 0, stream>>>(Kb, tab);
    attn_kernel<<<dim3(16, 64), 256, 0, stream>>>(Qb, Kb, Vt, Yb);
    gemm_nt<1><<<dim3(64, 16), 256, 0, stream>>>(Yb, wob, nullptr, nullptr, nullptr, out, 2048);
}

// Round 2
// 800.319 us; speedup vs baseline: 1.3532x; 1.3532x over previous
//
#include <hip/hip_runtime.h>
#include <math.h>

typedef unsigned short u16;
typedef __attribute__((ext_vector_type(4))) float f32x4;
typedef __attribute__((ext_vector_type(8))) __bf16 bf16x8;
typedef __attribute__((ext_vector_type(4))) unsigned short u16x4;
typedef __attribute__((ext_vector_type(8))) unsigned short u16x8;

// async global->LDS, 16B per lane; LDS dest must be wave-uniform base + lane*16
#define GLL16(gp, lp) __builtin_amdgcn_global_load_lds( \
    (__attribute__((address_space(1))) void*)(void*)(gp), \
    (__attribute__((address_space(3))) void*)(void*)(lp), 16, 0, 0)

__device__ __forceinline__ u16 f2bf(float x) {            // RNE
    unsigned u = __float_as_uint(x);
    return (u16)((u + 0x7FFFu + ((u >> 16) & 1u)) >> 16);
}
__device__ __forceinline__ float bf2f(u16 h) { return __uint_as_float(((unsigned)h) << 16); }

__device__ __forceinline__ f32x4 mfma16(bf16x8 a, bf16x8 b, f32x4 c) {
    return __builtin_amdgcn_mfma_f32_16x16x32_bf16(a, b, c, 0, 0, 0);
}

// ---------------- fp32 -> bf16 conversion ----------------
__global__ void cvt_f32_bf16(const float* __restrict__ s, u16* __restrict__ d, int n4) {
    int i = blockIdx.x * 256 + threadIdx.x;
    if (i < n4) {
        float4 v = ((const float4*)s)[i];
        u16x4 o = { f2bf(v.x), f2bf(v.y), f2bf(v.z), f2bf(v.w) };
        ((u16x4*)d)[i] = o;
    }
}

// ---------------- rope table: cos/sin of 2*theta (double rotary = rotate by 2theta) ----
__global__ void rope_table_k(float2* __restrict__ tab) {
    int id = blockIdx.x * 256 + threadIdx.x;   // 2048*64
    int t = id >> 6, j = id & 63;
    float freq = exp2f(-((float)(2 * j) / 128.f) * 13.287712379549449f);
    float ang = 2.f * (float)t * freq;
    float sv, cv;
    sincosf(ang, &sv, &cv);
    float2 r; r.x = cv; r.y = sv;
    tab[id] = r;
}

// ---------------- apply rotary in place on (B,T,H,128) bf16 tensor, with scale ----
__global__ void rope_apply_k(u16* __restrict__ X, const float2* __restrict__ tab, float scale) {
    const int id = blockIdx.x * 256 + threadIdx.x;   // 2^20 threads
    const int j8 = id & 7, h = (id >> 3) & 15, t = (id >> 7) & 2047, b = id >> 18;
    u16* p1 = X + (((size_t)(b * 2048 + t) * 16 + h) * 128) + j8 * 8;
    u16* p2 = p1 + 64;
    u16x8 a = *(const u16x8*)p1;
    u16x8 c2 = *(const u16x8*)p2;
    const float2* tb = tab + t * 64 + j8 * 8;
#pragma unroll
    for (int i = 0; i < 8; ++i) {
        float x1 = bf2f(a[i]), x2 = bf2f(c2[i]);
        float2 cs = tb[i];
        a[i]  = f2bf((x1 * cs.x + x2 * cs.y) * scale);
        c2[i] = f2bf((x2 * cs.x - x1 * cs.y) * scale);
    }
    *(u16x8*)p1 = a;
    *(u16x8*)p2 = c2;
}

// ---------------- NT GEMM: C[m][n] = sum_k A[m][k] * B[n][k], 128x128 tile, BK=32 ----
// MODE 0: fused QKV -> Q,K row-major (B,T,H,D); V transposed (B,H*D,T) via LDS transpose
// MODE 1: fp32 Out (M x 2048)
template <int MODE>
__global__ __launch_bounds__(256) void gemm_nt(const u16* __restrict__ A, const u16* __restrict__ Bw,
                                               u16* __restrict__ Qo, u16* __restrict__ Ko,
                                               u16* __restrict__ Vt, float* __restrict__ Out, int K) {
    __shared__ u16 As[128 * 32];
    __shared__ u16 Bs[128 * 32];
    const int tid = threadIdx.x;
    const int lane = tid & 63;
    const int qd = lane >> 4, ln = lane & 15;
    const int wid = tid >> 6;
    const int wx = wid & 1, wy = wid >> 1;
    const int m0 = blockIdx.x * 128, n0 = blockIdx.y * 128;
    const int c0 = tid, c1 = tid + 256;

    const u16* ga0 = A + (size_t)(m0 + (c0 >> 2)) * K + (c0 & 3) * 8;
    const u16* ga1 = A + (size_t)(m0 + (c1 >> 2)) * K + (c1 & 3) * 8;
    const u16* gb0 = Bw + (size_t)(n0 + (c0 >> 2)) * K + (c0 & 3) * 8;
    const u16* gb1 = Bw + (size_t)(n0 + (c1 >> 2)) * K + (c1 & 3) * 8;
    u16* la0 = &As[c0 * 8]; u16* la1 = &As[c1 * 8];
    u16* lb0 = &Bs[c0 * 8]; u16* lb1 = &Bs[c1 * 8];

    f32x4 acc[4][4];
#pragma unroll
    for (int mi = 0; mi < 4; ++mi)
#pragma unroll
        for (int ni = 0; ni < 4; ++ni) acc[mi][ni] = f32x4{0.f, 0.f, 0.f, 0.f};

    const int aoffb = (wy * 64 + ln) * 32 + qd * 8;
    const int boffb = (wx * 64 + ln) * 32 + qd * 8;

    const int niter = K >> 5;
    for (int kt = 0; kt < niter; ++kt) {
        __syncthreads();
        GLL16(ga0, la0); GLL16(ga1, la1);
        GLL16(gb0, lb0); GLL16(gb1, lb1);
        ga0 += 32; ga1 += 32; gb0 += 32; gb1 += 32;
        __syncthreads();
        bf16x8 af[4], bfr[4];
#pragma unroll
        for (int i = 0; i < 4; ++i) af[i] = *(const bf16x8*)&As[aoffb + i * 512];
#pragma unroll
        for (int i = 0; i < 4; ++i) bfr[i] = *(const bf16x8*)&Bs[boffb + i * 512];
#pragma unroll
        for (int mi = 0; mi < 4; ++mi)
#pragma unroll
            for (int ni = 0; ni < 4; ++ni)
                acc[mi][ni] = mfma16(af[mi], bfr[ni], acc[mi][ni]);
    }

    const int mg0 = m0 + wy * 64 + qd * 4;
    const int ng0 = n0 + wx * 64 + ln;
    if constexpr (MODE == 0) {
        const int sec = n0 >> 11;   // 0=Q 1=K 2=V, uniform per block
        if (sec == 2) {
            // LDS transpose: out tile is Vt[hd 128][t 128], write coalesced 16B rows
            __shared__ u16 Tr[64 * 128];   // [n_local 64][m 128], chunk-swizzled
            const int bb = m0 >> 11;
#pragma unroll
            for (int hhalf = 0; hhalf < 2; ++hhalf) {
                if (wx == hhalf) {
#pragma unroll
                    for (int mi = 0; mi < 4; ++mi) {
                        const int mbase = wy * 64 + mi * 16 + qd * 4;
                        const int mch = mbase >> 3, moff = mbase & 7;
#pragma unroll
                        for (int ni = 0; ni < 4; ++ni) {
                            const int nl = ni * 16 + ln;
                            u16x4 pk = { f2bf(acc[mi][ni][0]), f2bf(acc[mi][ni][1]),
                                         f2bf(acc[mi][ni][2]), f2bf(acc[mi][ni][3]) };
                            *(u16x4*)&Tr[nl * 128 + ((mch ^ (nl & 15)) * 8) + moff] = pk;
                        }
                    }
                }
                __syncthreads();
#pragma unroll
                for (int i = 0; i < 4; ++i) {
                    const int c = i * 256 + tid;
                    const int nl = c >> 4;
                    u16x8 v = *(const u16x8*)&Tr[c * 8];
                    const int mch = (c & 15) ^ (nl & 15);
                    const int hd = (n0 - 4096) + hhalf * 64 + nl;
                    *(u16x8*)&Vt[((size_t)(bb * 2048 + hd)) * 2048 + (m0 & 2047) + mch * 8] = v;
                }
                __syncthreads();
            }
        } else {
#pragma unroll
            for (int mi = 0; mi < 4; ++mi)
#pragma unroll
                for (int ni = 0; ni < 4; ++ni) {
                    const int ng = ng0 + ni * 16;
#pragma unroll
                    for (int r = 0; r < 4; ++r) {
                        const int m = mg0 + mi * 16 + r;
                        const u16 v = f2bf(acc[mi][ni][r]);
                        if (sec == 0) Qo[(size_t)m * 2048 + ng] = v;
                        else          Ko[(size_t)m * 2048 + (ng - 2048)] = v;
                    }
                }
        }
    } else {
#pragma unroll
        for (int mi = 0; mi < 4; ++mi)
#pragma unroll
            for (int ni = 0; ni < 4; ++ni) {
                const int ng = ng0 + ni * 16;
#pragma unroll
                for (int r = 0; r < 4; ++r)
                    Out[(size_t)(mg0 + mi * 16 + r) * 2048 + ng] = acc[mi][ni][r];
            }
    }
}

// ---------------- causal flash attention, dbuf K/V, single barrier/iter ----------------
// grid (16, B*H) with LPT order (big q-tiles first). block 256 = 4 waves, wave w owns
// Q rows [w*32, w*32+32). K/V tiles 64 wide, double-buffered. Dynamic LDS 80KB:
//   QP 16KB (Q staged in 2 halves, then P[128][64]) | Ks[2] 32KB | Vs[2] 32KB
// Q is pre-scaled by (1/sqrt(D))*log2(e) in rope. All LDS tiles chunk-XOR-swizzled.
__global__ __launch_bounds__(256, 2) void attn_kernel(const u16* __restrict__ Qb, const u16* __restrict__ Kb,
                                                      const u16* __restrict__ Vt, u16* __restrict__ Yb) {
    extern __shared__ u16 smem[];
    u16* QP = smem;                 // 8192 u16
    u16* KsB = smem + 8192;         // 2 x 8192 u16
    u16* VsB = smem + 8192 + 16384; // 2 x 8192 u16

    const int tid = threadIdx.x;
    const int lane = tid & 63;
    const int qd = lane >> 4, ln = lane & 15;
    const int wid = tid >> 6;
    const int wr = wid * 32;
    const int qt = (int)(gridDim.x - 1 - blockIdx.x);   // LPT: big tiles first
    const int bh = blockIdx.y;
    const int b = bh >> 4, h = bh & 15;
    const int q0 = qt * 128;
    const int wq = q0 + wr;          // first Q row of this wave
    const int nkt = 2 * qt + 2;

    const u16* Qbh = Qb + ((size_t)b * 2048 * 16 + h) * 128;
    const u16* Kbh = Kb + ((size_t)b * 2048 * 16 + h) * 128;
    const u16* Vbh = Vt + ((size_t)(b * 16 + h) * 128) * 2048;

    // per-thread staging descriptors (chunk-swizzled)
    const u16* gK[4]; const u16* gV[4]; int lC[4];
#pragma unroll
    for (int p = 0; p < 4; ++p) {
        const int c = p * 256 + tid;
        lC[p] = c * 8;
        { const int r = c >> 4, cc = (c & 15) ^ (r & 7);
          gK[p] = Kbh + (size_t)r * 2048 + cc * 8; }
        { const int rv = c >> 3, cc = (c & 7) ^ (rv & 7);
          gV[p] = Vbh + (size_t)rv * 2048 + cc * 8; }
    }

    // prefetch K/V tile 0 into buf 0
#pragma unroll
    for (int p = 0; p < 4; ++p) GLL16(gK[p], &KsB[lC[p]]);
#pragma unroll
    for (int p = 0; p < 4; ++p) GLL16(gV[p], &VsB[lC[p]]);
#pragma unroll
    for (int p = 0; p < 4; ++p) { gK[p] += 64 * 2048; gV[p] += 64; }

    // stage Q half 0 (rows q0..q0+63), extract frags for waves 0,1; then half 1
    bf16x8 qf[2][4];
#pragma unroll
    for (int p = 0; p < 4; ++p) {
        const int c = p * 256 + tid, lr = c >> 4, cc = (c & 15) ^ (lr & 7);
        GLL16(Qbh + (size_t)(q0 + lr) * 2048 + cc * 8, &QP[c * 8]);
    }
    __syncthreads();
    const int lrb = (wid & 1) * 32;
    if (wid < 2) {
#pragma unroll
        for (int mi = 0; mi < 2; ++mi)
#pragma unroll
            for (int ks = 0; ks < 4; ++ks) {
                const int lr = lrb + mi * 16 + ln;
                qf[mi][ks] = *(const bf16x8*)&QP[lr * 128 + (((ks * 4 + qd) ^ (lr & 7)) * 8)];
            }
    }
    __syncthreads();
#pragma unroll
    for (int p = 0; p < 4; ++p) {
        const int c = p * 256 + tid, lr = c >> 4, cc = (c & 15) ^ (lr & 7);
        GLL16(Qbh + (size_t)(q0 + 64 + lr) * 2048 + cc * 8, &QP[c * 8]);
    }
    __syncthreads();
    if (wid >= 2) {
#pragma unroll
        for (int mi = 0; mi < 2; ++mi)
#pragma unroll
            for (int ks = 0; ks < 4; ++ks) {
                const int lr = lrb + mi * 16 + ln;
                qf[mi][ks] = *(const bf16x8*)&QP[lr * 128 + (((ks * 4 + qd) ^ (lr & 7)) * 8)];
            }
    }
    __syncthreads();

    bf16x8 onesf;
#pragma unroll
    for (int i = 0; i < 8; ++i) onesf[i] = (__bf16)1.0f;

    f32x4 o[2][8];
#pragma unroll
    for (int mi = 0; mi < 2; ++mi)
#pragma unroll
        for (int di = 0; di < 8; ++di) o[mi][di] = f32x4{0.f, 0.f, 0.f, 0.f};
    f32x4 lacc[2] = { f32x4{0.f,0.f,0.f,0.f}, f32x4{0.f,0.f,0.f,0.f} };
    float Mr[2][4];
#pragma unroll
    for (int mi = 0; mi < 2; ++mi)
#pragma unroll
        for (int r = 0; r < 4; ++r) Mr[mi][r] = -1e30f;

    int curbuf = 0;
    for (int kt = 0; kt < nkt; ++kt) {
        const int k0 = kt * 64;
        __syncthreads();   // drains GLL of tile kt; frees buf !cur (reads done last iter)
        if (kt + 1 < nkt) {
            u16* kd = KsB + (curbuf ^ 1) * 8192;
            u16* vd = VsB + (curbuf ^ 1) * 8192;
#pragma unroll
            for (int p = 0; p < 4; ++p) GLL16(gK[p], &kd[lC[p]]);
#pragma unroll
            for (int p = 0; p < 4; ++p) GLL16(gV[p], &vd[lC[p]]);
        }
#pragma unroll
        for (int p = 0; p < 4; ++p) { gK[p] += 64 * 2048; gV[p] += 64; }

        if (k0 <= wq + 31) {   // else: tile fully masked for this wave -> skip (no barriers inside)
            const u16* Kc = KsB + curbuf * 8192;
            const u16* Vc = VsB + curbuf * 8192;
            // S = Q K^T
            f32x4 s[2][4];
#pragma unroll
            for (int mi = 0; mi < 2; ++mi)
#pragma unroll
                for (int ni = 0; ni < 4; ++ni) s[mi][ni] = f32x4{0.f, 0.f, 0.f, 0.f};
#pragma unroll
            for (int ks = 0; ks < 4; ++ks) {
                bf16x8 kf[4];
#pragma unroll
                for (int ni = 0; ni < 4; ++ni) {
                    const int row = ni * 16 + ln;
                    kf[ni] = *(const bf16x8*)&Kc[row * 128 + (((ks * 4 + qd) ^ (ln & 7)) * 8)];
                }
#pragma unroll
                for (int mi = 0; mi < 2; ++mi)
#pragma unroll
                    for (int ni = 0; ni < 4; ++ni)
                        s[mi][ni] = mfma16(qf[mi][ks], kf[ni], s[mi][ni]);
            }
            // causal mask only on diagonal tiles (wave-uniform branch)
            if (k0 + 63 > wq) {
#pragma unroll
                for (int mi = 0; mi < 2; ++mi)
#pragma unroll
                    for (int ni = 0; ni < 4; ++ni)
#pragma unroll
                        for (int r = 0; r < 4; ++r) {
                            const int qi = wq + mi * 16 + qd * 4 + r;
                            const int ki = k0 + ni * 16 + ln;
                            if (ki > qi) s[mi][ni][r] = -1e30f;
                        }
            }
            // row max: in-lane over ni, then 16-lane butterfly
            float rx[2][4];
#pragma unroll
            for (int mi = 0; mi < 2; ++mi)
#pragma unroll
                for (int r = 0; r < 4; ++r)
                    rx[mi][r] = fmaxf(fmaxf(s[mi][0][r], s[mi][1][r]), fmaxf(s[mi][2][r], s[mi][3][r]));
#pragma unroll
            for (int st = 1; st < 16; st <<= 1)
#pragma unroll
                for (int mi = 0; mi < 2; ++mi)
#pragma unroll
                    for (int r = 0; r < 4; ++r)
                        rx[mi][r] = fmaxf(rx[mi][r], __shfl_xor(rx[mi][r], st));
            float al[2][4];
            bool need = false;
#pragma unroll
            for (int mi = 0; mi < 2; ++mi)
#pragma unroll
                for (int r = 0; r < 4; ++r) {
                    const float nm = fmaxf(Mr[mi][r], rx[mi][r]);
                    al[mi][r] = exp2f(Mr[mi][r] - nm);
                    Mr[mi][r] = nm;
                    need |= (al[mi][r] != 1.0f);
                }
            if (__any(need)) {
#pragma unroll
                for (int mi = 0; mi < 2; ++mi) {
#pragma unroll
                    for (int r = 0; r < 4; ++r) lacc[mi][r] *= al[mi][r];
#pragma unroll
                    for (int di = 0; di < 8; ++di)
#pragma unroll
                        for (int r = 0; r < 4; ++r) o[mi][di][r] *= al[mi][r];
                }
            }
            // P = exp2(S - M), write to LDS (wave-local rows -> no barrier)
#pragma unroll
            for (int mi = 0; mi < 2; ++mi)
#pragma unroll
                for (int ni = 0; ni < 4; ++ni) {
                    const int cc0 = ni * 2 + (ln >> 3);
#pragma unroll
                    for (int r = 0; r < 4; ++r) {
                        const float p = exp2f(s[mi][ni][r] - Mr[mi][r]);
                        const int prow = wr + mi * 16 + qd * 4 + r;
                        QP[prow * 64 + ((cc0 ^ ((prow >> 1) & 7)) * 8) + (ln & 7)] = f2bf(p);
                    }
                }
            // O += P V ; L += P * ones (row sums via MFMA, lands in C-layout like Mr)
#pragma unroll
            for (int ks2 = 0; ks2 < 2; ++ks2) {
                bf16x8 pf[2];
#pragma unroll
                for (int mi = 0; mi < 2; ++mi) {
                    const int prow = wr + mi * 16 + ln;
                    pf[mi] = *(const bf16x8*)&QP[prow * 64 + (((ks2 * 4 + qd) ^ ((prow >> 1) & 7)) * 8)];
                }
                lacc[0] = mfma16(pf[0], onesf, lacc[0]);
                lacc[1] = mfma16(pf[1], onesf, lacc[1]);
#pragma unroll
                for (int di = 0; di < 8; ++di) {
                    const int row = di * 16 + ln;
                    bf16x8 vf = *(const bf16x8*)&Vc[row * 64 + (((ks2 * 4 + qd) ^ (ln & 7)) * 8)];
                    o[0][di] = mfma16(pf[0], vf, o[0][di]);
                    o[1][di] = mfma16(pf[1], vf, o[1][di]);
                }
            }
        }
        curbuf ^= 1;
    }
    // finalize: O / L, write Y (B,T,H,D) bf16
#pragma unroll
    for (int mi = 0; mi < 2; ++mi) {
        float inv[4];
#pragma unroll
        for (int r = 0; r < 4; ++r) inv[r] = 1.f / lacc[mi][r];
#pragma unroll
        for (int di = 0; di < 8; ++di)
#pragma unroll
            for (int r = 0; r < 4; ++r) {
                const int t = q0 + wr + mi * 16 + qd * 4 + r;
                const int d = di * 16 + ln;
                Yb[((size_t)((b * 2048 + t) * 16 + h)) * 128 + d] = f2bf(o[mi][di][r] * inv[r]);
            }
    }
}

// ---------------- launch ----------------
extern "C" void kernel_launch(void* const* d_in, const int* in_sizes, int n_in,
                              void* d_out, int out_size, void* d_ws, size_t ws_size,
                              hipStream_t stream) {
    const float* x  = (const float*)d_in[0];
    const float* wq = (const float*)d_in[1];
    const float* wk = (const float*)d_in[2];
    const float* wv = (const float*)d_in[3];
    const float* wo = (const float*)d_in[4];
    float* out = (float*)d_out;
    char* ws = (char*)d_ws;

    u16* xb     = (u16*)(ws);                          // 8192x2048 bf16; reused as Y after attn
    u16* wqkv   = (u16*)(ws + (size_t)33554432);       // 6144x2048 bf16
    u16* wob    = (u16*)(ws + (size_t)58720256);       // 2048x2048 bf16
    u16* Qb     = (u16*)(ws + (size_t)67108864);       // (B,T,H,D) bf16, pre-scaled by 1/sqrt(D)*log2e
    u16* Kb     = (u16*)(ws + (size_t)100663296);      // (B,T,H,D) bf16
    u16* Vt     = (u16*)(ws + (size_t)134217728);      // (B,H,D,T) bf16
    float2* tab = (float2*)(ws + (size_t)167772160);   // 2048x64 cos/sin(2theta)
    u16* Yb = xb;

    const float scl = 0.08838834764831845f * 1.4426950408889634f;

    cvt_f32_bf16<<<16384, 256, 0, stream>>>(x, xb, 4194304);
    cvt_f32_bf16<<<4096, 256, 0, stream>>>(wq, wqkv, 1048576);
    cvt_f32_bf16<<<4096, 256, 0, stream>>>(wk, wqkv + 4194304, 1048576);
    cvt_f32_bf16<<<4096, 256, 0, stream>>>(wv, wqkv + 8388608, 1048576);
    cvt_f32_bf16<<<4096, 256, 0, stream>>>(wo, wob, 1048576);
    rope_table_k<<<512, 256, 0, stream>>>(tab);

    gemm_nt<0><<<dim3(64, 48), 256, 0, stream>>>(xb, wqkv, Qb, Kb, Vt, nullptr, 2048);
    rope_apply_k<<<4096, 256, 0, stream>>>(Qb, tab, scl);
    rope_apply_k<<<4096, 256, 0, stream>>>(Kb, tab, 1.0f);

    hipFuncSetAttribute((const void*)attn_kernel, hipFuncAttributeMaxDynamicSharedMemorySize, 81920);
    attn_kernel<<<dim3(16, 64), 256, 81920, stream>>>(Qb, Kb, Vt, Yb);

    gemm_nt<1><<<dim3(64, 16), 256, 0, stream>>>(Yb, wob, nullptr, nullptr, nullptr, out, 2048);
}

// Round 4
// 775.996 us; speedup vs baseline: 1.3956x; 1.0313x over previous
//
#include <hip/hip_runtime.h>
#include <math.h>

typedef unsigned short u16;
typedef __attribute__((ext_vector_type(4))) float f32x4;
typedef __attribute__((ext_vector_type(8))) __bf16 bf16x8;
typedef __attribute__((ext_vector_type(4))) unsigned short u16x4;
typedef __attribute__((ext_vector_type(8))) unsigned short u16x8;

// async global->LDS, 16B per lane; LDS dest must be wave-uniform base + lane*16
#define GLL16(gp, lp) __builtin_amdgcn_global_load_lds( \
    (__attribute__((address_space(1))) void*)(void*)(gp), \
    (__attribute__((address_space(3))) void*)(void*)(lp), 16, 0, 0)

__device__ __forceinline__ u16 f2bf(float x) {            // RNE
    unsigned u = __float_as_uint(x);
    return (u16)((u + 0x7FFFu + ((u >> 16) & 1u)) >> 16);
}
__device__ __forceinline__ float bf2f(u16 h) { return __uint_as_float(((unsigned)h) << 16); }

__device__ __forceinline__ f32x4 mfma16(bf16x8 a, bf16x8 b, f32x4 c) {
    return __builtin_amdgcn_mfma_f32_16x16x32_bf16(a, b, c, 0, 0, 0);
}

// ---------------- fp32 -> bf16 conversion ----------------
__global__ void cvt_f32_bf16(const float* __restrict__ s, u16* __restrict__ d, int n4) {
    int i = blockIdx.x * 256 + threadIdx.x;
    if (i < n4) {
        float4 v = ((const float4*)s)[i];
        u16x4 o = { f2bf(v.x), f2bf(v.y), f2bf(v.z), f2bf(v.w) };
        ((u16x4*)d)[i] = o;
    }
}

// ---------------- rope table: cos/sin of 2*theta (double rotary = rotate by 2theta) ----
__global__ void rope_table_k(float2* __restrict__ tab) {
    int id = blockIdx.x * 256 + threadIdx.x;   // 2048*64
    int t = id >> 6, j = id & 63;
    float freq = exp2f(-((float)(2 * j) / 128.f) * 13.287712379549449f);
    float ang = 2.f * (float)t * freq;
    float sv, cv;
    sincosf(ang, &sv, &cv);
    float2 r; r.x = cv; r.y = sv;
    tab[id] = r;
}

// ---------------- NT GEMM: C[m][n] = sum_k A[m][k] * B[n][k], 128x128 tile, BK=32 ----
// MODE 0: fused QKV; rope+scale fused into Q/K epilogue (each n-tile == one head);
//         V written transposed (B,H*D,T). All epilogues via 32KB LDS, 16B stores.
// MODE 1: fp32 Out (M x 2048)
// XCD swizzle: ids congruent mod 8 share m_blk for NBY consecutive slots (A-strip L2 reuse).
template <int MODE>
__global__ __launch_bounds__(256) void gemm_nt(const u16* __restrict__ A, const u16* __restrict__ Bw,
                                               u16* __restrict__ Qo, u16* __restrict__ Ko,
                                               u16* __restrict__ Vt, float* __restrict__ Out,
                                               const float2* __restrict__ tab, float qscale, int K) {
    __shared__ u16 smem[MODE == 0 ? 16384 : 8192];   // K-loop: As(4096)+Bs(4096); MODE0 epilogue: 16384
    u16* As = smem;
    u16* Bs = smem + 4096;
    const int tid = threadIdx.x;
    const int lane = tid & 63;
    const int qd = lane >> 4, ln = lane & 15;
    const int wid = tid >> 6;
    const int wx = wid & 1, wy = wid >> 1;

    constexpr int NBY = (MODE == 0) ? 48 : 16;
    const int id = blockIdx.y * 64 + blockIdx.x;
    const int xcd = id & 7, slot = id >> 3;
    const int m0 = ((slot / NBY) * 8 + xcd) * 128;
    const int n0 = (slot % NBY) * 128;

    const int c0 = tid, c1 = tid + 256;
    const u16* ga0 = A + (size_t)(m0 + (c0 >> 2)) * K + (c0 & 3) * 8;
    const u16* ga1 = A + (size_t)(m0 + (c1 >> 2)) * K + (c1 & 3) * 8;
    const u16* gb0 = Bw + (size_t)(n0 + (c0 >> 2)) * K + (c0 & 3) * 8;
    const u16* gb1 = Bw + (size_t)(n0 + (c1 >> 2)) * K + (c1 & 3) * 8;
    u16* la0 = &As[c0 * 8]; u16* la1 = &As[c1 * 8];
    u16* lb0 = &Bs[c0 * 8]; u16* lb1 = &Bs[c1 * 8];

    f32x4 acc[4][4];
#pragma unroll
    for (int mi = 0; mi < 4; ++mi)
#pragma unroll
        for (int ni = 0; ni < 4; ++ni) acc[mi][ni] = f32x4{0.f, 0.f, 0.f, 0.f};

    const int aoffb = (wy * 64 + ln) * 32 + qd * 8;
    const int boffb = (wx * 64 + ln) * 32 + qd * 8;

    const int niter = K >> 5;
    for (int kt = 0; kt < niter; ++kt) {
        __syncthreads();
        GLL16(ga0, la0); GLL16(ga1, la1);
        GLL16(gb0, lb0); GLL16(gb1, lb1);
        ga0 += 32; ga1 += 32; gb0 += 32; gb1 += 32;
        __syncthreads();
        bf16x8 af[4], bfr[4];
#pragma unroll
        for (int i = 0; i < 4; ++i) af[i] = *(const bf16x8*)&As[aoffb + i * 512];
#pragma unroll
        for (int i = 0; i < 4; ++i) bfr[i] = *(const bf16x8*)&Bs[boffb + i * 512];
#pragma unroll
        for (int mi = 0; mi < 4; ++mi)
#pragma unroll
            for (int ni = 0; ni < 4; ++ni)
                acc[mi][ni] = mfma16(af[mi], bfr[ni], acc[mi][ni]);
    }
    __syncthreads();   // K-loop LDS dead; epilogue reuses it

    if constexpr (MODE == 0) {
        const int sec = n0 >> 11;   // 0=Q 1=K 2=V, uniform per block
        if (sec <= 1) {
            // stage C tile [m 128][d 128], chunk-swizzled: chunk' = (d>>3) ^ (m&15)
#pragma unroll
            for (int mi = 0; mi < 4; ++mi)
#pragma unroll
                for (int ni = 0; ni < 4; ++ni) {
                    const int col = wx * 64 + ni * 16 + ln;
                    const int cc = col >> 3, co = col & 7;
#pragma unroll
                    for (int r = 0; r < 4; ++r) {
                        const int row = wy * 64 + mi * 16 + qd * 4 + r;
                        smem[row * 128 + ((cc ^ (row & 15)) * 8) + co] = f2bf(acc[mi][ni][r]);
                    }
                }
            __syncthreads();
            const float qs = (sec == 0) ? qscale : 1.0f;
            u16* dstb = (sec == 0 ? Qo : Ko);
#pragma unroll
            for (int it = 0; it < 4; ++it) {
                const int c = it * 256 + tid;          // 1024 items: m=c>>3 (0..127), d-octet=c&7
                const int m = c >> 3, d8 = c & 7;
                const u16x8 lo = *(const u16x8*)&smem[m * 128 + ((d8 ^ (m & 15)) * 8)];
                const u16x8 hi = *(const u16x8*)&smem[m * 128 + (((d8 + 8) ^ (m & 15)) * 8)];
                const int t = (m0 + m) & 2047;
                const float2* tb = tab + t * 64 + d8 * 8;
                u16x8 o1, o2;
#pragma unroll
                for (int i = 0; i < 8; ++i) {
                    const float x1 = bf2f(lo[i]), x2 = bf2f(hi[i]);
                    const float2 cs = tb[i];
                    o1[i] = f2bf((x1 * cs.x + x2 * cs.y) * qs);
                    o2[i] = f2bf((x2 * cs.x - x1 * cs.y) * qs);
                }
                u16* dst = dstb + (size_t)(m0 + m) * 2048 + (n0 & 2047) + d8 * 8;
                *(u16x8*)dst = o1;
                *(u16x8*)(dst + 64) = o2;
            }
        } else {
            // V transpose: stage [n 128][m 128] chunk-swizzled, stream out rows of Vt
            const int bb = m0 >> 11;
#pragma unroll
            for (int mi = 0; mi < 4; ++mi) {
                const int mbase = wy * 64 + mi * 16 + qd * 4;
                const int mch = mbase >> 3, moff = mbase & 7;
#pragma unroll
                for (int ni = 0; ni < 4; ++ni) {
                    const int nl = wx * 64 + ni * 16 + ln;
                    u16x4 pk = { f2bf(acc[mi][ni][0]), f2bf(acc[mi][ni][1]),
                                 f2bf(acc[mi][ni][2]), f2bf(acc[mi][ni][3]) };
                    *(u16x4*)&smem[nl * 128 + ((mch ^ (nl & 15)) * 8) + moff] = pk;
                }
            }
            __syncthreads();
#pragma unroll
            for (int i = 0; i < 8; ++i) {
                const int c = i * 256 + tid;
                const int nl = c >> 4;
                const u16x8 v = *(const u16x8*)&smem[c * 8];
                const int mch = (c & 15) ^ (nl & 15);
                const int hd = (n0 - 4096) + nl;
                *(u16x8*)&Vt[((size_t)(bb * 2048 + hd)) * 2048 + (m0 & 2047) + mch * 8] = v;
            }
        }
    } else {
        const int mg0 = m0 + wy * 64 + qd * 4;
        const int ng0 = n0 + wx * 64 + ln;
#pragma unroll
        for (int mi = 0; mi < 4; ++mi)
#pragma unroll
            for (int ni = 0; ni < 4; ++ni) {
                const int ng = ng0 + ni * 16;
#pragma unroll
                for (int r = 0; r < 4; ++r)
                    Out[(size_t)(mg0 + mi * 16 + r) * 2048 + ng] = acc[mi][ni][r];
            }
    }
}

// ---------------- causal flash attention, dbuf K/V, single barrier/iter ----------------
__global__ __launch_bounds__(256, 2) void attn_kernel(const u16* __restrict__ Qb, const u16* __restrict__ Kb,
                                                      const u16* __restrict__ Vt, u16* __restrict__ Yb) {
    extern __shared__ u16 smem[];
    u16* QP = smem;                 // 8192 u16
    u16* KsB = smem + 8192;         // 2 x 8192 u16
    u16* VsB = smem + 8192 + 16384; // 2 x 8192 u16

    const int tid = threadIdx.x;
    const int lane = tid & 63;
    const int qd = lane >> 4, ln = lane & 15;
    const int wid = tid >> 6;
    const int wr = wid * 32;
    const int qt = (int)(gridDim.x - 1 - blockIdx.x);   // LPT: big tiles first
    const int bh = blockIdx.y;
    const int b = bh >> 4, h = bh & 15;
    const int q0 = qt * 128;
    const int wq = q0 + wr;
    const int nkt = 2 * qt + 2;

    const u16* Qbh = Qb + ((size_t)b * 2048 * 16 + h) * 128;
    const u16* Kbh = Kb + ((size_t)b * 2048 * 16 + h) * 128;
    const u16* Vbh = Vt + ((size_t)(b * 16 + h) * 128) * 2048;

    const u16* gK[4]; const u16* gV[4]; int lC[4];
#pragma unroll
    for (int p = 0; p < 4; ++p) {
        const int c = p * 256 + tid;
        lC[p] = c * 8;
        { const int r = c >> 4, cc = (c & 15) ^ (r & 7);
          gK[p] = Kbh + (size_t)r * 2048 + cc * 8; }
        { const int rv = c >> 3, cc = (c & 7) ^ (rv & 7);
          gV[p] = Vbh + (size_t)rv * 2048 + cc * 8; }
    }

#pragma unroll
    for (int p = 0; p < 4; ++p) GLL16(gK[p], &KsB[lC[p]]);
#pragma unroll
    for (int p = 0; p < 4; ++p) GLL16(gV[p], &VsB[lC[p]]);
#pragma unroll
    for (int p = 0; p < 4; ++p) { gK[p] += 64 * 2048; gV[p] += 64; }

    bf16x8 qf[2][4];
#pragma unroll
    for (int p = 0; p < 4; ++p) {
        const int c = p * 256 + tid, lr = c >> 4, cc = (c & 15) ^ (lr & 7);
        GLL16(Qbh + (size_t)(q0 + lr) * 2048 + cc * 8, &QP[c * 8]);
    }
    __syncthreads();
    const int lrb = (wid & 1) * 32;
    if (wid < 2) {
#pragma unroll
        for (int mi = 0; mi < 2; ++mi)
#pragma unroll
            for (int ks = 0; ks < 4; ++ks) {
                const int lr = lrb + mi * 16 + ln;
                qf[mi][ks] = *(const bf16x8*)&QP[lr * 128 + (((ks * 4 + qd) ^ (lr & 7)) * 8)];
            }
    }
    __syncthreads();
#pragma unroll
    for (int p = 0; p < 4; ++p) {
        const int c = p * 256 + tid, lr = c >> 4, cc = (c & 15) ^ (lr & 7);
        GLL16(Qbh + (size_t)(q0 + 64 + lr) * 2048 + cc * 8, &QP[c * 8]);
    }
    __syncthreads();
    if (wid >= 2) {
#pragma unroll
        for (int mi = 0; mi < 2; ++mi)
#pragma unroll
            for (int ks = 0; ks < 4; ++ks) {
                const int lr = lrb + mi * 16 + ln;
                qf[mi][ks] = *(const bf16x8*)&QP[lr * 128 + (((ks * 4 + qd) ^ (lr & 7)) * 8)];
            }
    }
    __syncthreads();

    bf16x8 onesf;
#pragma unroll
    for (int i = 0; i < 8; ++i) onesf[i] = (__bf16)1.0f;

    f32x4 o[2][8];
#pragma unroll
    for (int mi = 0; mi < 2; ++mi)
#pragma unroll
        for (int di = 0; di < 8; ++di) o[mi][di] = f32x4{0.f, 0.f, 0.f, 0.f};
    f32x4 lacc[2] = { f32x4{0.f,0.f,0.f,0.f}, f32x4{0.f,0.f,0.f,0.f} };
    float Mr[2][4];
#pragma unroll
    for (int mi = 0; mi < 2; ++mi)
#pragma unroll
        for (int r = 0; r < 4; ++r) Mr[mi][r] = -1e30f;

    int curbuf = 0;
    for (int kt = 0; kt < nkt; ++kt) {
        const int k0 = kt * 64;
        __syncthreads();
        if (kt + 1 < nkt) {
            u16* kd = KsB + (curbuf ^ 1) * 8192;
            u16* vd = VsB + (curbuf ^ 1) * 8192;
#pragma unroll
            for (int p = 0; p < 4; ++p) GLL16(gK[p], &kd[lC[p]]);
#pragma unroll
            for (int p = 0; p < 4; ++p) GLL16(gV[p], &vd[lC[p]]);
        }
#pragma unroll
        for (int p = 0; p < 4; ++p) { gK[p] += 64 * 2048; gV[p] += 64; }

        if (k0 <= wq + 31) {
            const u16* Kc = KsB + curbuf * 8192;
            const u16* Vc = VsB + curbuf * 8192;
            f32x4 s[2][4];
#pragma unroll
            for (int mi = 0; mi < 2; ++mi)
#pragma unroll
                for (int ni = 0; ni < 4; ++ni) s[mi][ni] = f32x4{0.f, 0.f, 0.f, 0.f};
#pragma unroll
            for (int ks = 0; ks < 4; ++ks) {
                bf16x8 kf[4];
#pragma unroll
                for (int ni = 0; ni < 4; ++ni) {
                    const int row = ni * 16 + ln;
                    kf[ni] = *(const bf16x8*)&Kc[row * 128 + (((ks * 4 + qd) ^ (ln & 7)) * 8)];
                }
#pragma unroll
                for (int mi = 0; mi < 2; ++mi)
#pragma unroll
                    for (int ni = 0; ni < 4; ++ni)
                        s[mi][ni] = mfma16(qf[mi][ks], kf[ni], s[mi][ni]);
            }
            if (k0 + 63 > wq) {
#pragma unroll
                for (int mi = 0; mi < 2; ++mi)
#pragma unroll
                    for (int ni = 0; ni < 4; ++ni)
#pragma unroll
                        for (int r = 0; r < 4; ++r) {
                            const int qi = wq + mi * 16 + qd * 4 + r;
                            const int ki = k0 + ni * 16 + ln;
                            if (ki > qi) s[mi][ni][r] = -1e30f;
                        }
            }
            float rx[2][4];
#pragma unroll
            for (int mi = 0; mi < 2; ++mi)
#pragma unroll
                for (int r = 0; r < 4; ++r)
                    rx[mi][r] = fmaxf(fmaxf(s[mi][0][r], s[mi][1][r]), fmaxf(s[mi][2][r], s[mi][3][r]));
#pragma unroll
            for (int st = 1; st < 16; st <<= 1)
#pragma unroll
                for (int mi = 0; mi < 2; ++mi)
#pragma unroll
                    for (int r = 0; r < 4; ++r)
                        rx[mi][r] = fmaxf(rx[mi][r], __shfl_xor(rx[mi][r], st));
            float al[2][4];
            bool need = false;
#pragma unroll
            for (int mi = 0; mi < 2; ++mi)
#pragma unroll
                for (int r = 0; r < 4; ++r) {
                    const float nm = fmaxf(Mr[mi][r], rx[mi][r]);
                    al[mi][r] = exp2f(Mr[mi][r] - nm);
                    Mr[mi][r] = nm;
                    need |= (al[mi][r] != 1.0f);
                }
            if (__any(need)) {
#pragma unroll
                for (int mi = 0; mi < 2; ++mi) {
#pragma unroll
                    for (int r = 0; r < 4; ++r) lacc[mi][r] *= al[mi][r];
#pragma unroll
                    for (int di = 0; di < 8; ++di)
#pragma unroll
                        for (int r = 0; r < 4; ++r) o[mi][di][r] *= al[mi][r];
                }
            }
#pragma unroll
            for (int mi = 0; mi < 2; ++mi)
#pragma unroll
                for (int ni = 0; ni < 4; ++ni) {
                    const int cc0 = ni * 2 + (ln >> 3);
#pragma unroll
                    for (int r = 0; r < 4; ++r) {
                        const float p = exp2f(s[mi][ni][r] - Mr[mi][r]);
                        const int prow = wr + mi * 16 + qd * 4 + r;
                        QP[prow * 64 + ((cc0 ^ ((prow >> 1) & 7)) * 8) + (ln & 7)] = f2bf(p);
                    }
                }
#pragma unroll
            for (int ks2 = 0; ks2 < 2; ++ks2) {
                bf16x8 pf[2];
#pragma unroll
                for (int mi = 0; mi < 2; ++mi) {
                    const int prow = wr + mi * 16 + ln;
                    pf[mi] = *(const bf16x8*)&QP[prow * 64 + (((ks2 * 4 + qd) ^ ((prow >> 1) & 7)) * 8)];
                }
                lacc[0] = mfma16(pf[0], onesf, lacc[0]);
                lacc[1] = mfma16(pf[1], onesf, lacc[1]);
#pragma unroll
                for (int di = 0; di < 8; ++di) {
                    const int row = di * 16 + ln;
                    bf16x8 vf = *(const bf16x8*)&Vc[row * 64 + (((ks2 * 4 + qd) ^ (ln & 7)) * 8)];
                    o[0][di] = mfma16(pf[0], vf, o[0][di]);
                    o[1][di] = mfma16(pf[1], vf, o[1][di]);
                }
            }
        }
        curbuf ^= 1;
    }
#pragma unroll
    for (int mi = 0; mi < 2; ++mi) {
        float inv[4];
#pragma unroll
        for (int r = 0; r < 4; ++r) inv[r] = 1.f / lacc[mi][r];
#pragma unroll
        for (int di = 0; di < 8; ++di)
#pragma unroll
            for (int r = 0; r < 4; ++r) {
                const int t = q0 + wr + mi * 16 + qd * 4 + r;
                const int d = di * 16 + ln;
                Yb[((size_t)((b * 2048 + t) * 16 + h)) * 128 + d] = f2bf(o[mi][di][r] * inv[r]);
            }
    }
}

// ---------------- launch ----------------
extern "C" void kernel_launch(void* const* d_in, const int* in_sizes, int n_in,
                              void* d_out, int out_size, void* d_ws, size_t ws_size,
                              hipStream_t stream) {
    const float* x  = (const float*)d_in[0];
    const float* wq = (const float*)d_in[1];
    const float* wk = (const float*)d_in[2];
    const float* wv = (const float*)d_in[3];
    const float* wo = (const float*)d_in[4];
    float* out = (float*)d_out;
    char* ws = (char*)d_ws;

    u16* xb     = (u16*)(ws);                          // 8192x2048 bf16; reused as Y after attn
    u16* wqkv   = (u16*)(ws + (size_t)33554432);       // 6144x2048 bf16
    u16* wob    = (u16*)(ws + (size_t)58720256);       // 2048x2048 bf16
    u16* Qb     = (u16*)(ws + (size_t)67108864);       // (B,T,H,D) bf16, pre-scaled by 1/sqrt(D)*log2e
    u16* Kb     = (u16*)(ws + (size_t)100663296);      // (B,T,H,D) bf16
    u16* Vt     = (u16*)(ws + (size_t)134217728);      // (B,H,D,T) bf16
    float2* tab = (float2*)(ws + (size_t)167772160);   // 2048x64 cos/sin(2theta)
    u16* Yb = xb;

    const float scl = 0.08838834764831845f * 1.4426950408889634f;

    cvt_f32_bf16<<<16384, 256, 0, stream>>>(x, xb, 4194304);
    cvt_f32_bf16<<<4096, 256, 0, stream>>>(wq, wqkv, 1048576);
    cvt_f32_bf16<<<4096, 256, 0, stream>>>(wk, wqkv + 4194304, 1048576);
    cvt_f32_bf16<<<4096, 256, 0, stream>>>(wv, wqkv + 8388608, 1048576);
    cvt_f32_bf16<<<4096, 256, 0, stream>>>(wo, wob, 1048576);
    rope_table_k<<<512, 256, 0, stream>>>(tab);

    gemm_nt<0><<<dim3(64, 48), 256, 0, stream>>>(xb, wqkv, Qb, Kb, Vt, nullptr, tab, scl, 2048);

    hipFuncSetAttribute((const void*)attn_kernel, hipFuncAttributeMaxDynamicSharedMemorySize, 81920);
    attn_kernel<<<dim3(16, 64), 256, 81920, stream>>>(Qb, Kb, Vt, Yb);

    gemm_nt<1><<<dim3(64, 16), 256, 0, stream>>>(Yb, wob, nullptr, nullptr, nullptr, out, tab, 1.0f, 2048);
}